// Round 1
// baseline (449.503 us; speedup 1.0000x reference)
//
#include <hip/hip_runtime.h>
#include <hip/hip_bf16.h>
#include <math.h>

#define BB 2
#define SS 1024
#define DD 1024
#define HH 16
#define HDD 64
#define MASK_VAL -10000.0f

// ---------------------------------------------------------------------------
// x = h[0] + h[1]   (sum the two additive shares)
// ---------------------------------------------------------------------------
__global__ __launch_bounds__(256) void k_sum_shares(const float* __restrict__ h,
                                                    float* __restrict__ x, int n4) {
    int i = blockIdx.x * blockDim.x + threadIdx.x;
    int stride = gridDim.x * blockDim.x;
    const float4* h0 = (const float4*)h;
    const float4* h1 = (const float4*)(h + (size_t)n4 * 4);
    float4* xo = (float4*)x;
    for (int idx = i; idx < n4; idx += stride) {
        float4 a = h0[idx];
        float4 b = h1[idx];
        xo[idx] = make_float4(a.x + b.x, a.y + b.y, a.z + b.z, a.w + b.w);
    }
}

// ---------------------------------------------------------------------------
// C[m][n] = sum_k A[m][k] * W[n][k] + bias[n]      (torch Linear: x @ W.T + b)
// Tiles: 128x128, BK=16, 256 threads, 8x8 micro (split 4+4 to keep LDS reads
// 2-way-broadcast conflict-free).
// ---------------------------------------------------------------------------
#define GBM 128
#define GBN 128
#define GBK 16

__device__ __forceinline__ void gemm_body(const float* __restrict__ A,
                                          const float* __restrict__ W,
                                          const float* __restrict__ bias,
                                          float* __restrict__ C,
                                          int M, int N, int K) {
    __shared__ float As[GBK][GBM + 4];
    __shared__ float Ws[GBK][GBN + 4];
    const int bm = blockIdx.y * GBM;
    const int bn = blockIdx.x * GBN;
    const int tid = threadIdx.x;
    const int tx = tid & 15;
    const int ty = tid >> 4;

    float acc[8][8];
#pragma unroll
    for (int i = 0; i < 8; ++i)
#pragma unroll
        for (int j = 0; j < 8; ++j) acc[i][j] = 0.f;

    const int lr = tid >> 2;          // 0..63 (row within 64-row half)
    const int lk = (tid & 3) << 2;    // 0,4,8,12

    for (int k0 = 0; k0 < K; k0 += GBK) {
#pragma unroll
        for (int p = 0; p < 2; ++p) {
            int r = (p << 6) + lr;    // 0..127
            float4 a4 = *(const float4*)(A + (size_t)(bm + r) * K + k0 + lk);
            As[lk + 0][r] = a4.x; As[lk + 1][r] = a4.y;
            As[lk + 2][r] = a4.z; As[lk + 3][r] = a4.w;
            float4 w4 = *(const float4*)(W + (size_t)(bn + r) * K + k0 + lk);
            Ws[lk + 0][r] = w4.x; Ws[lk + 1][r] = w4.y;
            Ws[lk + 2][r] = w4.z; Ws[lk + 3][r] = w4.w;
        }
        __syncthreads();
#pragma unroll
        for (int kk = 0; kk < GBK; ++kk) {
            float a[8], w[8];
            *(float4*)&a[0] = *(const float4*)&As[kk][ty << 2];
            *(float4*)&a[4] = *(const float4*)&As[kk][64 + (ty << 2)];
            *(float4*)&w[0] = *(const float4*)&Ws[kk][tx << 2];
            *(float4*)&w[4] = *(const float4*)&Ws[kk][64 + (tx << 2)];
#pragma unroll
            for (int i = 0; i < 8; ++i)
#pragma unroll
                for (int j = 0; j < 8; ++j)
                    acc[i][j] = fmaf(a[i], w[j], acc[i][j]);
        }
        __syncthreads();
    }

#pragma unroll
    for (int i = 0; i < 8; ++i) {
        int row = bm + ((i < 4) ? ((ty << 2) + i) : (64 + (ty << 2) + (i - 4)));
#pragma unroll
        for (int jg = 0; jg < 2; ++jg) {
            int col = bn + (jg << 6) + (tx << 2);
            float4 o;
            o.x = acc[i][jg * 4 + 0] + bias[col + 0];
            o.y = acc[i][jg * 4 + 1] + bias[col + 1];
            o.z = acc[i][jg * 4 + 2] + bias[col + 2];
            o.w = acc[i][jg * 4 + 3] + bias[col + 3];
            *(float4*)(C + (size_t)row * N + col) = o;
        }
    }
}

// Fused Q/K/V projection: blockIdx.z selects which weight/out.
__global__ __launch_bounds__(256) void k_gemm_qkv(
    const float* __restrict__ x,
    const float* __restrict__ wq, const float* __restrict__ bq,
    const float* __restrict__ wk, const float* __restrict__ bk,
    const float* __restrict__ wv, const float* __restrict__ bv,
    float* __restrict__ q, float* __restrict__ k, float* __restrict__ v,
    int M, int N, int K) {
    const float* W; const float* bias; float* C;
    if (blockIdx.z == 0)      { W = wq; bias = bq; C = q; }
    else if (blockIdx.z == 1) { W = wk; bias = bk; C = k; }
    else                      { W = wv; bias = bv; C = v; }
    gemm_body(x, W, bias, C, M, N, K);
}

__global__ __launch_bounds__(256) void k_gemm_out(
    const float* __restrict__ A, const float* __restrict__ W,
    const float* __restrict__ bias, float* __restrict__ C,
    int M, int N, int K) {
    gemm_body(A, W, bias, C, M, N, K);
}

// ---------------------------------------------------------------------------
// Fused flash-style attention, fp32.
// grid: (S/64, B*H). block: 256 threads = 16x16, 4x4 micro-tile.
// Q/K staged transposed in LDS ([d][row]) so the d-loop reads are float4;
// V row-major; P round-trips through LDS for the PV GEMM.
// Online softmax state (m,l) per row, replicated across the row's 16 lanes.
// ---------------------------------------------------------------------------
__global__ __launch_bounds__(256) void k_attn(
    const float* __restrict__ q, const float* __restrict__ kmat,
    const float* __restrict__ v, const float* __restrict__ mask,
    float* __restrict__ ctx) {
    const int bh = blockIdx.y;
    const int b = bh >> 4;      // H = 16
    const int h = bh & 15;
    const int q0 = blockIdx.x << 6;
    const int tid = threadIdx.x;
    const int tx = tid & 15;
    const int ty = tid >> 4;
    const float scale = 0.125f;  // 1/sqrt(64)

    __shared__ float QT[HDD][64 + 4];   // [d][r]
    __shared__ float KT[HDD][64 + 4];   // [d][c]
    __shared__ float Vs[64][HDD + 4];   // [c][d]
    __shared__ float Ps[64][64 + 4];    // [r][c]

    // stage Q tile transposed (rows q0..q0+63, head slice h)
    const float* qbase = q + ((size_t)(b * SS + q0) * DD + h * HDD);
#pragma unroll
    for (int p = 0; p < 4; ++p) {
        int r = (p << 4) + ty;
        float4 t = *(const float4*)(qbase + (size_t)r * DD + (tx << 2));
        QT[(tx << 2) + 0][r] = t.x; QT[(tx << 2) + 1][r] = t.y;
        QT[(tx << 2) + 2][r] = t.z; QT[(tx << 2) + 3][r] = t.w;
    }

    float m_r[4], l_r[4], O[4][4];
#pragma unroll
    for (int i = 0; i < 4; ++i) {
        m_r[i] = -3.0e38f; l_r[i] = 0.f;
#pragma unroll
        for (int j = 0; j < 4; ++j) O[i][j] = 0.f;
    }

    for (int t0 = 0; t0 < SS; t0 += 64) {
        __syncthreads();  // prev PV done (and QT visible on first iter)
        const float* kb = kmat + ((size_t)(b * SS + t0) * DD + h * HDD);
        const float* vb = v + ((size_t)(b * SS + t0) * DD + h * HDD);
#pragma unroll
        for (int p = 0; p < 4; ++p) {
            int r = (p << 4) + ty;
            float4 t = *(const float4*)(kb + (size_t)r * DD + (tx << 2));
            KT[(tx << 2) + 0][r] = t.x; KT[(tx << 2) + 1][r] = t.y;
            KT[(tx << 2) + 2][r] = t.z; KT[(tx << 2) + 3][r] = t.w;
            float4 u = *(const float4*)(vb + (size_t)r * DD + (tx << 2));
            *(float4*)&Vs[r][tx << 2] = u;
        }
        __syncthreads();

        // S = scale * Q K^T + additive_mask
        float s[4][4];
#pragma unroll
        for (int i = 0; i < 4; ++i)
#pragma unroll
            for (int j = 0; j < 4; ++j) s[i][j] = 0.f;
#pragma unroll 8
        for (int dd = 0; dd < HDD; ++dd) {
            float4 av = *(const float4*)&QT[dd][ty << 2];
            float4 wv4 = *(const float4*)&KT[dd][tx << 2];
            float a[4] = {av.x, av.y, av.z, av.w};
            float w[4] = {wv4.x, wv4.y, wv4.z, wv4.w};
#pragma unroll
            for (int i = 0; i < 4; ++i)
#pragma unroll
                for (int j = 0; j < 4; ++j)
                    s[i][j] = fmaf(a[i], w[j], s[i][j]);
        }
        float addv[4];
#pragma unroll
        for (int j = 0; j < 4; ++j)
            addv[j] = (1.0f - mask[b * SS + t0 + (tx << 2) + j]) * MASK_VAL;
#pragma unroll
        for (int i = 0; i < 4; ++i)
#pragma unroll
            for (int j = 0; j < 4; ++j)
                s[i][j] = s[i][j] * scale + addv[j];

        // online softmax
        float rm[4], alpha[4], rs[4];
#pragma unroll
        for (int i = 0; i < 4; ++i) {
            rm[i] = fmaxf(fmaxf(s[i][0], s[i][1]), fmaxf(s[i][2], s[i][3]));
        }
#pragma unroll
        for (int i = 0; i < 4; ++i) {
#pragma unroll
            for (int mo = 1; mo < 16; mo <<= 1)
                rm[i] = fmaxf(rm[i], __shfl_xor(rm[i], mo, 16));
            float mn = fmaxf(m_r[i], rm[i]);
            alpha[i] = __expf(m_r[i] - mn);
            m_r[i] = mn;
        }
        float pv_[4][4];
#pragma unroll
        for (int i = 0; i < 4; ++i) {
            rs[i] = 0.f;
#pragma unroll
            for (int j = 0; j < 4; ++j) {
                pv_[i][j] = __expf(s[i][j] - m_r[i]);
                rs[i] += pv_[i][j];
            }
        }
#pragma unroll
        for (int i = 0; i < 4; ++i) {
#pragma unroll
            for (int mo = 1; mo < 16; mo <<= 1)
                rs[i] += __shfl_xor(rs[i], mo, 16);
            l_r[i] = l_r[i] * alpha[i] + rs[i];
#pragma unroll
            for (int j = 0; j < 4; ++j) O[i][j] *= alpha[i];
            float4 pw = make_float4(pv_[i][0], pv_[i][1], pv_[i][2], pv_[i][3]);
            *(float4*)&Ps[(ty << 2) + i][tx << 2] = pw;
        }
        __syncthreads();

        // O += P @ V
#pragma unroll 4
        for (int c4 = 0; c4 < 64; c4 += 4) {
            float4 p4[4];
#pragma unroll
            for (int i = 0; i < 4; ++i)
                p4[i] = *(const float4*)&Ps[(ty << 2) + i][c4];
#pragma unroll
            for (int cc = 0; cc < 4; ++cc) {
                float4 vv = *(const float4*)&Vs[c4 + cc][tx << 2];
                float pc[4] = {p4[0].x, p4[1].x, p4[2].x, p4[3].x};
                if (cc == 1) { pc[0] = p4[0].y; pc[1] = p4[1].y; pc[2] = p4[2].y; pc[3] = p4[3].y; }
                if (cc == 2) { pc[0] = p4[0].z; pc[1] = p4[1].z; pc[2] = p4[2].z; pc[3] = p4[3].z; }
                if (cc == 3) { pc[0] = p4[0].w; pc[1] = p4[1].w; pc[2] = p4[2].w; pc[3] = p4[3].w; }
#pragma unroll
                for (int i = 0; i < 4; ++i) {
                    O[i][0] = fmaf(pc[i], vv.x, O[i][0]);
                    O[i][1] = fmaf(pc[i], vv.y, O[i][1]);
                    O[i][2] = fmaf(pc[i], vv.z, O[i][2]);
                    O[i][3] = fmaf(pc[i], vv.w, O[i][3]);
                }
            }
        }
    }

    // finalize + write ctx in [B,S,D] layout (head h slice) => transpose-free
    float* cb = ctx + ((size_t)(b * SS + q0) * DD + h * HDD);
#pragma unroll
    for (int i = 0; i < 4; ++i) {
        float inv = 1.0f / l_r[i];
        float4 o = make_float4(O[i][0] * inv, O[i][1] * inv, O[i][2] * inv, O[i][3] * inv);
        *(float4*)(cb + (size_t)((ty << 2) + i) * DD + (tx << 2)) = o;
    }
}

// ---------------------------------------------------------------------------
extern "C" void kernel_launch(void* const* d_in, const int* in_sizes, int n_in,
                              void* d_out, int out_size, void* d_ws, size_t ws_size,
                              hipStream_t stream) {
    const float* h    = (const float*)d_in[0];   // [2,B,S,D]
    const float* mask = (const float*)d_in[1];   // [B,S]
    const float* wq   = (const float*)d_in[2];
    const float* bq   = (const float*)d_in[3];
    const float* wk   = (const float*)d_in[4];
    const float* bk   = (const float*)d_in[5];
    const float* wv   = (const float*)d_in[6];
    const float* bv   = (const float*)d_in[7];
    const float* wo   = (const float*)d_in[8];
    const float* bo   = (const float*)d_in[9];
    float* out = (float*)d_out;

    const int BSD = BB * SS * DD;                // 2097152
    float* ws = (float*)d_ws;
    float* x   = ws;
    float* q   = ws + (size_t)BSD;
    float* k   = ws + (size_t)2 * BSD;
    float* v   = ws + (size_t)3 * BSD;
    float* ctx = ws + (size_t)4 * BSD;

    const int M = BB * SS;   // 2048
    const int N = DD;        // 1024
    const int K = DD;        // 1024

    k_sum_shares<<<2048, 256, 0, stream>>>(h, x, BSD / 4);

    dim3 gqkv(N / GBN, M / GBM, 3);
    k_gemm_qkv<<<gqkv, 256, 0, stream>>>(x, wq, bq, wk, bk, wv, bv, q, k, v, M, N, K);

    dim3 gattn(SS / 64, BB * HH);
    k_attn<<<gattn, 256, 0, stream>>>(q, k, v, mask, ctx);

    dim3 gout(N / GBN, M / GBM);
    k_gemm_out<<<gout, 256, 0, stream>>>(ctx, wo, bo, out, M, N, K);
}

// Round 2
// 197.401 us; speedup vs baseline: 2.2771x; 2.2771x over previous
//
#include <hip/hip_runtime.h>
#include <hip/hip_bf16.h>

#define BB 2
#define SS 1024
#define DD 1024
#define HH 16
#define HDD 64
#define MASK_VAL -10000.0f
#define BSD (BB * SS * DD)   // 2097152

typedef __attribute__((ext_vector_type(8))) short bf16x8;
typedef __attribute__((ext_vector_type(4))) short short4v;
typedef __attribute__((ext_vector_type(4))) float f32x4;

__device__ __forceinline__ short f2bf(float f) {
    union { float f; unsigned u; } v; v.f = f;
    unsigned r = v.u + 0x7FFFu + ((v.u >> 16) & 1u);   // RN-even
    return (short)(r >> 16);
}

// ---------------------------------------------------------------------------
// x_bf = bf16(h[0] + h[1])
// ---------------------------------------------------------------------------
__global__ __launch_bounds__(256) void k_prep_x(const float* __restrict__ h,
                                                short* __restrict__ xbf) {
    int i = blockIdx.x * blockDim.x + threadIdx.x;   // 0 .. BSD/8
    const float4* h0 = (const float4*)h;
    const float4* h1 = (const float4*)(h + (size_t)BSD);
    float4 a0 = h0[2 * i], a1 = h0[2 * i + 1];
    float4 b0 = h1[2 * i], b1 = h1[2 * i + 1];
    bf16x8 o;
    o[0] = f2bf(a0.x + b0.x); o[1] = f2bf(a0.y + b0.y);
    o[2] = f2bf(a0.z + b0.z); o[3] = f2bf(a0.w + b0.w);
    o[4] = f2bf(a1.x + b1.x); o[5] = f2bf(a1.y + b1.y);
    o[6] = f2bf(a1.z + b1.z); o[7] = f2bf(a1.w + b1.w);
    ((bf16x8*)xbf)[i] = o;
}

// ---------------------------------------------------------------------------
// weights fp32 -> bf16 (4 matrices, blockIdx.z selects)
// ---------------------------------------------------------------------------
__global__ __launch_bounds__(256) void k_prep_w(const float* __restrict__ wq,
                                                const float* __restrict__ wk,
                                                const float* __restrict__ wv,
                                                const float* __restrict__ wo,
                                                short* __restrict__ wbf) {
    int z = blockIdx.z;
    const float* src = (z == 0) ? wq : (z == 1) ? wk : (z == 2) ? wv : wo;
    short* dst = wbf + (size_t)z * (DD * DD);
    int i = blockIdx.x * blockDim.x + threadIdx.x;   // 0 .. DD*DD/8
    const float4* s4 = (const float4*)src;
    float4 a0 = s4[2 * i], a1 = s4[2 * i + 1];
    bf16x8 o;
    o[0] = f2bf(a0.x); o[1] = f2bf(a0.y); o[2] = f2bf(a0.z); o[3] = f2bf(a0.w);
    o[4] = f2bf(a1.x); o[5] = f2bf(a1.y); o[6] = f2bf(a1.z); o[7] = f2bf(a1.w);
    ((bf16x8*)dst)[i] = o;
}

// ---------------------------------------------------------------------------
// bf16 MFMA GEMM, m97 structure: 128x128 tile, BK=32, 256 threads (4 waves,
// 2x2), each wave 64x64 = 4x4 fragments of 16x16x32. B^T input:
// C[m][n] = sum_k A[m][k] * W[n][k] + bias[n].  A,W bf16 row-major [.,K].
// Staging via global_load_lds width=16, linear LDS.
// ---------------------------------------------------------------------------
#define TM 128
#define TN 128
#define TK 32

__device__ __forceinline__ void gemm_bf16_body(const short* __restrict__ A,
                                               const short* __restrict__ W,
                                               const float* __restrict__ bias,
                                               float* __restrict__ C,
                                               int K, int N, int bm, int bn) {
    __shared__ __align__(16) short As[TM * TK];   // [row][k] linear
    __shared__ __align__(16) short Bs[TN * TK];
    const int tid = threadIdx.x;
    const int lane = tid & 63;
    const int wid = tid >> 6;         // 0..3
    const int wm = wid >> 1;          // 0..1
    const int wn = wid & 1;           // 0..1
    const int lr = lane & 15;         // fragment row/col
    const int kq = lane >> 4;         // 0..3  k-quarter (8 bf16 each)

    f32x4 acc[4][4];
#pragma unroll
    for (int i = 0; i < 4; ++i)
#pragma unroll
        for (int j = 0; j < 4; ++j) acc[i][j] = (f32x4)0.0f;

    for (int k0 = 0; k0 < K; k0 += TK) {
        // stage A,B tiles: 2 x 4KB issues each (256 lanes x 16B)
#pragma unroll
        for (int i = 0; i < 2; ++i) {
            int t = i * 256 + tid;
            int r = t >> 2;               // 0..127
            int kk = (t & 3) << 3;        // 0,8,16,24
            const short* ga = A + (size_t)(bm + r) * K + k0 + kk;
            __builtin_amdgcn_global_load_lds(
                (const __attribute__((address_space(1))) unsigned*)ga,
                (__attribute__((address_space(3))) unsigned*)&As[t * 8], 16, 0, 0);
            const short* gb = W + (size_t)(bn + r) * K + k0 + kk;
            __builtin_amdgcn_global_load_lds(
                (const __attribute__((address_space(1))) unsigned*)gb,
                (__attribute__((address_space(3))) unsigned*)&Bs[t * 8], 16, 0, 0);
        }
        __syncthreads();   // drains vmcnt + barrier

        bf16x8 af[4], bfr[4];
#pragma unroll
        for (int f = 0; f < 4; ++f) {
            af[f]  = *(const bf16x8*)&As[(wm * 64 + f * 16 + lr) * TK + kq * 8];
            bfr[f] = *(const bf16x8*)&Bs[(wn * 64 + f * 16 + lr) * TK + kq * 8];
        }
#pragma unroll
        for (int fm = 0; fm < 4; ++fm)
#pragma unroll
            for (int fn = 0; fn < 4; ++fn)
                acc[fm][fn] = __builtin_amdgcn_mfma_f32_16x16x32_bf16(
                    af[fm], bfr[fn], acc[fm][fn], 0, 0, 0);
        __syncthreads();   // all reads done before next stage overwrites
    }

    // epilogue: C/D layout col=lane&15, row=(lane>>4)*4+reg
#pragma unroll
    for (int fm = 0; fm < 4; ++fm) {
        int row0 = bm + wm * 64 + fm * 16 + kq * 4;
#pragma unroll
        for (int fn = 0; fn < 4; ++fn) {
            int col = bn + wn * 64 + fn * 16 + lr;
            float bv = bias[col];
#pragma unroll
            for (int j = 0; j < 4; ++j)
                C[(size_t)(row0 + j) * N + col] = acc[fm][fn][j] + bv;
        }
    }
}

__global__ __launch_bounds__(256) void k_gemm_qkv(
    const short* __restrict__ xbf, const short* __restrict__ wbf,
    const float* __restrict__ bq, const float* __restrict__ bk,
    const float* __restrict__ bv,
    float* __restrict__ q, float* __restrict__ k, float* __restrict__ v) {
    int z = blockIdx.z;
    const short* W = wbf + (size_t)z * (DD * DD);
    const float* bias = (z == 0) ? bq : (z == 1) ? bk : bv;
    float* C = (z == 0) ? q : (z == 1) ? k : v;
    gemm_bf16_body(xbf, W, bias, C, DD, DD, blockIdx.y * TM, blockIdx.x * TN);
}

__global__ __launch_bounds__(256) void k_gemm_out(
    const short* __restrict__ A, const short* __restrict__ W,
    const float* __restrict__ bias, float* __restrict__ C) {
    gemm_bf16_body(A, W, bias, C, DD, DD, blockIdx.y * TM, blockIdx.x * TN);
}

// ---------------------------------------------------------------------------
// Fused flash-style attention, fp32 (unchanged from R1 except bf16 ctx out).
// grid: (S/64, B*H). block 256 = 16x16, 4x4 micro.
// ---------------------------------------------------------------------------
__global__ __launch_bounds__(256) void k_attn(
    const float* __restrict__ q, const float* __restrict__ kmat,
    const float* __restrict__ v, const float* __restrict__ mask,
    short* __restrict__ ctx) {
    const int bh = blockIdx.y;
    const int b = bh >> 4;
    const int h = bh & 15;
    const int q0 = blockIdx.x << 6;
    const int tid = threadIdx.x;
    const int tx = tid & 15;
    const int ty = tid >> 4;
    const float scale = 0.125f;

    __shared__ float QT[HDD][64 + 4];
    __shared__ float KT[HDD][64 + 4];
    __shared__ float Vs[64][HDD + 4];
    __shared__ float Ps[64][64 + 4];

    const float* qbase = q + ((size_t)(b * SS + q0) * DD + h * HDD);
#pragma unroll
    for (int p = 0; p < 4; ++p) {
        int r = (p << 4) + ty;
        float4 t = *(const float4*)(qbase + (size_t)r * DD + (tx << 2));
        QT[(tx << 2) + 0][r] = t.x; QT[(tx << 2) + 1][r] = t.y;
        QT[(tx << 2) + 2][r] = t.z; QT[(tx << 2) + 3][r] = t.w;
    }

    float m_r[4], l_r[4], O[4][4];
#pragma unroll
    for (int i = 0; i < 4; ++i) {
        m_r[i] = -3.0e38f; l_r[i] = 0.f;
#pragma unroll
        for (int j = 0; j < 4; ++j) O[i][j] = 0.f;
    }

    for (int t0 = 0; t0 < SS; t0 += 64) {
        __syncthreads();
        const float* kb = kmat + ((size_t)(b * SS + t0) * DD + h * HDD);
        const float* vb = v + ((size_t)(b * SS + t0) * DD + h * HDD);
#pragma unroll
        for (int p = 0; p < 4; ++p) {
            int r = (p << 4) + ty;
            float4 t = *(const float4*)(kb + (size_t)r * DD + (tx << 2));
            KT[(tx << 2) + 0][r] = t.x; KT[(tx << 2) + 1][r] = t.y;
            KT[(tx << 2) + 2][r] = t.z; KT[(tx << 2) + 3][r] = t.w;
            float4 u = *(const float4*)(vb + (size_t)r * DD + (tx << 2));
            *(float4*)&Vs[r][tx << 2] = u;
        }
        __syncthreads();

        float s[4][4];
#pragma unroll
        for (int i = 0; i < 4; ++i)
#pragma unroll
            for (int j = 0; j < 4; ++j) s[i][j] = 0.f;
#pragma unroll 8
        for (int dd = 0; dd < HDD; ++dd) {
            float4 av = *(const float4*)&QT[dd][ty << 2];
            float4 wv4 = *(const float4*)&KT[dd][tx << 2];
            float a[4] = {av.x, av.y, av.z, av.w};
            float w[4] = {wv4.x, wv4.y, wv4.z, wv4.w};
#pragma unroll
            for (int i = 0; i < 4; ++i)
#pragma unroll
                for (int j = 0; j < 4; ++j)
                    s[i][j] = fmaf(a[i], w[j], s[i][j]);
        }
        float addv[4];
#pragma unroll
        for (int j = 0; j < 4; ++j)
            addv[j] = (1.0f - mask[b * SS + t0 + (tx << 2) + j]) * MASK_VAL;
#pragma unroll
        for (int i = 0; i < 4; ++i)
#pragma unroll
            for (int j = 0; j < 4; ++j)
                s[i][j] = s[i][j] * scale + addv[j];

        float rm[4], alpha[4], rs[4];
#pragma unroll
        for (int i = 0; i < 4; ++i)
            rm[i] = fmaxf(fmaxf(s[i][0], s[i][1]), fmaxf(s[i][2], s[i][3]));
#pragma unroll
        for (int i = 0; i < 4; ++i) {
#pragma unroll
            for (int mo = 1; mo < 16; mo <<= 1)
                rm[i] = fmaxf(rm[i], __shfl_xor(rm[i], mo, 16));
            float mn = fmaxf(m_r[i], rm[i]);
            alpha[i] = __expf(m_r[i] - mn);
            m_r[i] = mn;
        }
        float pv_[4][4];
#pragma unroll
        for (int i = 0; i < 4; ++i) {
            rs[i] = 0.f;
#pragma unroll
            for (int j = 0; j < 4; ++j) {
                pv_[i][j] = __expf(s[i][j] - m_r[i]);
                rs[i] += pv_[i][j];
            }
        }
#pragma unroll
        for (int i = 0; i < 4; ++i) {
#pragma unroll
            for (int mo = 1; mo < 16; mo <<= 1)
                rs[i] += __shfl_xor(rs[i], mo, 16);
            l_r[i] = l_r[i] * alpha[i] + rs[i];
#pragma unroll
            for (int j = 0; j < 4; ++j) O[i][j] *= alpha[i];
            float4 pw = make_float4(pv_[i][0], pv_[i][1], pv_[i][2], pv_[i][3]);
            *(float4*)&Ps[(ty << 2) + i][tx << 2] = pw;
        }
        __syncthreads();

#pragma unroll 4
        for (int c4 = 0; c4 < 64; c4 += 4) {
            float4 p4[4];
#pragma unroll
            for (int i = 0; i < 4; ++i)
                p4[i] = *(const float4*)&Ps[(ty << 2) + i][c4];
#pragma unroll
            for (int cc = 0; cc < 4; ++cc) {
                float4 vv = *(const float4*)&Vs[c4 + cc][tx << 2];
                float pc[4] = {p4[0].x, p4[1].x, p4[2].x, p4[3].x};
                if (cc == 1) { pc[0] = p4[0].y; pc[1] = p4[1].y; pc[2] = p4[2].y; pc[3] = p4[3].y; }
                if (cc == 2) { pc[0] = p4[0].z; pc[1] = p4[1].z; pc[2] = p4[2].z; pc[3] = p4[3].z; }
                if (cc == 3) { pc[0] = p4[0].w; pc[1] = p4[1].w; pc[2] = p4[2].w; pc[3] = p4[3].w; }
#pragma unroll
                for (int i = 0; i < 4; ++i) {
                    O[i][0] = fmaf(pc[i], vv.x, O[i][0]);
                    O[i][1] = fmaf(pc[i], vv.y, O[i][1]);
                    O[i][2] = fmaf(pc[i], vv.z, O[i][2]);
                    O[i][3] = fmaf(pc[i], vv.w, O[i][3]);
                }
            }
        }
    }

    // finalize; write ctx as bf16 in [B,S,D] layout (head slice h)
    short* cb = ctx + ((size_t)(b * SS + q0) * DD + h * HDD);
#pragma unroll
    for (int i = 0; i < 4; ++i) {
        float inv = 1.0f / l_r[i];
        short4v o;
        o.x = f2bf(O[i][0] * inv); o.y = f2bf(O[i][1] * inv);
        o.z = f2bf(O[i][2] * inv); o.w = f2bf(O[i][3] * inv);
        *(short4v*)(cb + (size_t)((ty << 2) + i) * DD + (tx << 2)) = o;
    }
}

// ---------------------------------------------------------------------------
extern "C" void kernel_launch(void* const* d_in, const int* in_sizes, int n_in,
                              void* d_out, int out_size, void* d_ws, size_t ws_size,
                              hipStream_t stream) {
    const float* h    = (const float*)d_in[0];
    const float* mask = (const float*)d_in[1];
    const float* wq   = (const float*)d_in[2];
    const float* bq   = (const float*)d_in[3];
    const float* wk   = (const float*)d_in[4];
    const float* bk   = (const float*)d_in[5];
    const float* wv   = (const float*)d_in[6];
    const float* bv   = (const float*)d_in[7];
    const float* wo   = (const float*)d_in[8];
    const float* bo   = (const float*)d_in[9];
    float* out = (float*)d_out;

    // workspace layout (40 MB total, same footprint as R1)
    short* x_bf  = (short*)d_ws;                          // 4 MB
    short* w_bf  = x_bf + (size_t)BSD;                    // 8 MB (4 x 1M bf16)
    char*  base  = (char*)d_ws;
    float* q     = (float*)(base + (12u << 20));          // 8 MB
    float* k     = (float*)(base + (20u << 20));          // 8 MB
    float* v     = (float*)(base + (28u << 20));          // 8 MB
    short* ctxbf = (short*)(base + (36u << 20));          // 4 MB

    k_prep_x<<<BSD / 8 / 256, 256, 0, stream>>>(h, x_bf);
    k_prep_w<<<dim3(DD * DD / 8 / 256, 1, 4), 256, 0, stream>>>(wq, wk, wv, wo, w_bf);

    dim3 gqkv(DD / TN, BB * SS / TM, 3);
    k_gemm_qkv<<<gqkv, 256, 0, stream>>>(x_bf, w_bf, bq, bk, bv, q, k, v);

    dim3 gattn(SS / 64, BB * HH);
    k_attn<<<gattn, 256, 0, stream>>>(q, k, v, mask, ctxbf);

    dim3 gout(DD / TN, BB * SS / TM);
    k_gemm_out<<<gout, 256, 0, stream>>>(ctxbf, w_bf + (size_t)3 * DD * DD, bo, out);
}

// Round 3
// 97.865 us; speedup vs baseline: 4.5931x; 2.0171x over previous
//
#include <hip/hip_runtime.h>
#include <hip/hip_bf16.h>

#define BB 2
#define SS 1024
#define DD 1024
#define HH 16
#define HDD 64
#define MASK_VAL -10000.0f
#define BSD (BB * SS * DD)   // 2097152

typedef __attribute__((ext_vector_type(8))) short bf16x8;
typedef __attribute__((ext_vector_type(4))) short short4v;
typedef __attribute__((ext_vector_type(4))) float f32x4;

__device__ __forceinline__ short f2bf(float f) {
    union { float f; unsigned u; } v; v.f = f;
    unsigned r = v.u + 0x7FFFu + ((v.u >> 16) & 1u);   // RN-even
    return (short)(r >> 16);
}

// ---------------------------------------------------------------------------
// x_bf = bf16(h[0] + h[1])
// ---------------------------------------------------------------------------
__global__ __launch_bounds__(256) void k_prep_x(const float* __restrict__ h,
                                                short* __restrict__ xbf) {
    int i = blockIdx.x * blockDim.x + threadIdx.x;
    const float4* h0 = (const float4*)h;
    const float4* h1 = (const float4*)(h + (size_t)BSD);
    float4 a0 = h0[2 * i], a1 = h0[2 * i + 1];
    float4 b0 = h1[2 * i], b1 = h1[2 * i + 1];
    bf16x8 o;
    o[0] = f2bf(a0.x + b0.x); o[1] = f2bf(a0.y + b0.y);
    o[2] = f2bf(a0.z + b0.z); o[3] = f2bf(a0.w + b0.w);
    o[4] = f2bf(a1.x + b1.x); o[5] = f2bf(a1.y + b1.y);
    o[6] = f2bf(a1.z + b1.z); o[7] = f2bf(a1.w + b1.w);
    ((bf16x8*)xbf)[i] = o;
}

__global__ __launch_bounds__(256) void k_prep_w(const float* __restrict__ wq,
                                                const float* __restrict__ wk,
                                                const float* __restrict__ wv,
                                                const float* __restrict__ wo,
                                                short* __restrict__ wbf) {
    int z = blockIdx.z;
    const float* src = (z == 0) ? wq : (z == 1) ? wk : (z == 2) ? wv : wo;
    short* dst = wbf + (size_t)z * (DD * DD);
    int i = blockIdx.x * blockDim.x + threadIdx.x;
    const float4* s4 = (const float4*)src;
    float4 a0 = s4[2 * i], a1 = s4[2 * i + 1];
    bf16x8 o;
    o[0] = f2bf(a0.x); o[1] = f2bf(a0.y); o[2] = f2bf(a0.z); o[3] = f2bf(a0.w);
    o[4] = f2bf(a1.x); o[5] = f2bf(a1.y); o[6] = f2bf(a1.z); o[7] = f2bf(a1.w);
    ((bf16x8*)dst)[i] = o;
}

// ---------------------------------------------------------------------------
// bf16 MFMA GEMM, 128x128 tile, BK=32. epi: 0 = f32 out (+bias),
// 1 = bf16 out [B,S,D] (+bias), 2 = bf16 V^T out [B,H,64,S] (+bias).
// ---------------------------------------------------------------------------
#define TM 128
#define TN 128
#define TK 32

__device__ __forceinline__ void gemm_bf16_body(const short* __restrict__ A,
                                               const short* __restrict__ W,
                                               const float* __restrict__ bias,
                                               float* __restrict__ Cf,
                                               short* __restrict__ Cb,
                                               int epi, int K, int N,
                                               int bm, int bn) {
    __shared__ __align__(16) short As[TM * TK];
    __shared__ __align__(16) short Bs[TN * TK];
    const int tid = threadIdx.x;
    const int lane = tid & 63;
    const int wid = tid >> 6;
    const int wm = wid >> 1;
    const int wn = wid & 1;
    const int lr = lane & 15;
    const int kq = lane >> 4;

    f32x4 acc[4][4];
#pragma unroll
    for (int i = 0; i < 4; ++i)
#pragma unroll
        for (int j = 0; j < 4; ++j) acc[i][j] = (f32x4)0.0f;

    for (int k0 = 0; k0 < K; k0 += TK) {
#pragma unroll
        for (int i = 0; i < 2; ++i) {
            int t = i * 256 + tid;
            int r = t >> 2;
            int kk = (t & 3) << 3;
            const short* ga = A + (size_t)(bm + r) * K + k0 + kk;
            __builtin_amdgcn_global_load_lds(
                (const __attribute__((address_space(1))) unsigned*)ga,
                (__attribute__((address_space(3))) unsigned*)&As[t * 8], 16, 0, 0);
            const short* gb = W + (size_t)(bn + r) * K + k0 + kk;
            __builtin_amdgcn_global_load_lds(
                (const __attribute__((address_space(1))) unsigned*)gb,
                (__attribute__((address_space(3))) unsigned*)&Bs[t * 8], 16, 0, 0);
        }
        __syncthreads();

        bf16x8 af[4], bfr[4];
#pragma unroll
        for (int f = 0; f < 4; ++f) {
            af[f]  = *(const bf16x8*)&As[(wm * 64 + f * 16 + lr) * TK + kq * 8];
            bfr[f] = *(const bf16x8*)&Bs[(wn * 64 + f * 16 + lr) * TK + kq * 8];
        }
#pragma unroll
        for (int fm = 0; fm < 4; ++fm)
#pragma unroll
            for (int fn = 0; fn < 4; ++fn)
                acc[fm][fn] = __builtin_amdgcn_mfma_f32_16x16x32_bf16(
                    af[fm], bfr[fn], acc[fm][fn], 0, 0, 0);
        __syncthreads();
    }

    // epilogue. C/D layout: col = lane&15, row = (lane>>4)*4 + reg.
#pragma unroll
    for (int fm = 0; fm < 4; ++fm) {
        int row0 = bm + wm * 64 + fm * 16 + kq * 4;
#pragma unroll
        for (int fn = 0; fn < 4; ++fn) {
            int col = bn + wn * 64 + fn * 16 + lr;
            float bv = bias[col];
            if (epi == 0) {
#pragma unroll
                for (int j = 0; j < 4; ++j)
                    Cf[(size_t)(row0 + j) * N + col] = acc[fm][fn][j] + bv;
            } else if (epi == 1) {
#pragma unroll
                for (int j = 0; j < 4; ++j)
                    Cb[(size_t)(row0 + j) * N + col] = f2bf(acc[fm][fn][j] + bv);
            } else {
                // V^T: [B][H][64][S]; rows row0..row0+3 are contiguous in S
                int bidx = row0 >> 10, s0 = row0 & 1023;
                size_t addr = ((size_t)(bidx * HH + (col >> 6)) * HDD + (col & 63)) * SS + s0;
                short4v o;
                o.x = f2bf(acc[fm][fn][0] + bv); o.y = f2bf(acc[fm][fn][1] + bv);
                o.z = f2bf(acc[fm][fn][2] + bv); o.w = f2bf(acc[fm][fn][3] + bv);
                *(short4v*)&Cb[addr] = o;
            }
        }
    }
}

__global__ __launch_bounds__(256) void k_gemm_qkv(
    const short* __restrict__ xbf, const short* __restrict__ wbf,
    const float* __restrict__ bq, const float* __restrict__ bk,
    const float* __restrict__ bv,
    short* __restrict__ qb, short* __restrict__ kb, short* __restrict__ vt) {
    int z = blockIdx.z;
    const short* W = wbf + (size_t)z * (DD * DD);
    const float* bias = (z == 0) ? bq : (z == 1) ? bk : bv;
    short* C = (z == 0) ? qb : (z == 1) ? kb : vt;
    int epi = (z == 2) ? 2 : 1;
    gemm_bf16_body(xbf, W, bias, nullptr, C, epi, DD, DD,
                   blockIdx.y * TM, blockIdx.x * TN);
}

__global__ __launch_bounds__(256) void k_gemm_out(
    const short* __restrict__ A, const short* __restrict__ W,
    const float* __restrict__ bias, float* __restrict__ C) {
    gemm_bf16_body(A, W, bias, C, nullptr, 0, DD, DD,
                   blockIdx.y * TM, blockIdx.x * TN);
}

// ---------------------------------------------------------------------------
// MFMA flash attention. grid (S/64, B*H), 256 thr = 4 waves x 16 q-rows.
// K-tile [kv][d], V^T-tile [d][kv]: 64x64 bf16, double-buffered LDS,
// global_load_lds linear dest + XOR chunk-swizzled global source,
// XOR-swizzled ds_read_b128 (conflict-free). Counted vmcnt(4) barriers.
// ---------------------------------------------------------------------------
__global__ __launch_bounds__(256) void k_attn(
    const short* __restrict__ qb, const short* __restrict__ kb,
    const short* __restrict__ vt, const float* __restrict__ mask,
    short* __restrict__ ctx) {
    __shared__ __align__(16) short Kls[2][64 * 64];
    __shared__ __align__(16) short Vls[2][64 * 64];
    __shared__ __align__(16) short Pls[4][16 * 64];

    const int bh = blockIdx.y;
    const int b = bh >> 4;
    const int h = bh & 15;
    const int q0 = blockIdx.x << 6;
    const int tid = threadIdx.x;
    const int lane = tid & 63;
    const int w = tid >> 6;
    const int lr = lane & 15;
    const int kq = lane >> 4;
    const float scale = 0.125f;

    const short* khead = kb + (size_t)b * SS * DD + h * HDD;       // + kv*DD + d
    const short* vhead = vt + (size_t)bh * HDD * SS;               // + d*SS + kv
    const float* maskp = mask + b * SS;

    // Q fragment in registers: row = lr, k-quarter kq
    bf16x8 qf[2];
    {
        const short* qrow = qb + ((size_t)(b * SS + q0 + w * 16 + lr)) * DD + h * HDD;
        qf[0] = *(const bf16x8*)(qrow + kq * 8);
        qf[1] = *(const bf16x8*)(qrow + 32 + kq * 8);
    }

    // stage one 64-tile pair into buffer `bi`
    auto stage = [&](int t0, int bi) {
        const short* kbase = khead + (size_t)t0 * DD;
        const short* vbase = vhead + t0;
#pragma unroll
        for (int i = 0; i < 2; ++i) {
            int t = i * 256 + tid;
            int r = t >> 3;
            int cs = (t & 7) ^ (r & 7);     // source chunk (involution swizzle)
            __builtin_amdgcn_global_load_lds(
                (const __attribute__((address_space(1))) unsigned*)(kbase + (size_t)r * DD + cs * 8),
                (__attribute__((address_space(3))) unsigned*)&Kls[bi][t * 8], 16, 0, 0);
            __builtin_amdgcn_global_load_lds(
                (const __attribute__((address_space(1))) unsigned*)(vbase + (size_t)r * SS + cs * 8),
                (__attribute__((address_space(3))) unsigned*)&Vls[bi][t * 8], 16, 0, 0);
        }
    };

    float m_r[4], l_r[4];
    f32x4 O[4];
#pragma unroll
    for (int j = 0; j < 4; ++j) { m_r[j] = -3.0e38f; l_r[j] = 0.f; O[j] = (f32x4)0.0f; }

    auto body = [&](int t0, int cur) {
        const short* Kb = &Kls[cur][0];
        const short* Vb = &Vls[cur][0];
        short* Pw = &Pls[w][0];

        // QK^T: S[q=kq*4+j][kv=fc*16+lr]
        bf16x8 kf[4][2];
#pragma unroll
        for (int fc = 0; fc < 4; ++fc) {
            int row = fc * 16 + lr;
            int sw = lr & 7;
            kf[fc][0] = *(const bf16x8*)&Kb[row * 64 + ((kq ^ sw) << 3)];
            kf[fc][1] = *(const bf16x8*)&Kb[row * 64 + (((4 + kq) ^ sw) << 3)];
        }
        f32x4 sacc[4];
#pragma unroll
        for (int fc = 0; fc < 4; ++fc) sacc[fc] = (f32x4)0.0f;
#pragma unroll
        for (int fc = 0; fc < 4; ++fc) {
            sacc[fc] = __builtin_amdgcn_mfma_f32_16x16x32_bf16(qf[0], kf[fc][0], sacc[fc], 0, 0, 0);
            sacc[fc] = __builtin_amdgcn_mfma_f32_16x16x32_bf16(qf[1], kf[fc][1], sacc[fc], 0, 0, 0);
        }

        float addv[4];
#pragma unroll
        for (int fc = 0; fc < 4; ++fc)
            addv[fc] = (1.0f - maskp[t0 + fc * 16 + lr]) * MASK_VAL;

        float s[4][4];
#pragma unroll
        for (int fc = 0; fc < 4; ++fc)
#pragma unroll
            for (int j = 0; j < 4; ++j)
                s[fc][j] = sacc[fc][j] * scale + addv[fc];

        // online softmax over kv (16 lanes x 4 fc per row)
        float rm[4], alpha[4], rs[4];
#pragma unroll
        for (int j = 0; j < 4; ++j)
            rm[j] = fmaxf(fmaxf(s[0][j], s[1][j]), fmaxf(s[2][j], s[3][j]));
#pragma unroll
        for (int j = 0; j < 4; ++j) {
#pragma unroll
            for (int mo = 1; mo < 16; mo <<= 1)
                rm[j] = fmaxf(rm[j], __shfl_xor(rm[j], mo, 16));
            float mn = fmaxf(m_r[j], rm[j]);
            alpha[j] = __expf(m_r[j] - mn);
            m_r[j] = mn;
        }
#pragma unroll
        for (int j = 0; j < 4; ++j) rs[j] = 0.f;
#pragma unroll
        for (int fc = 0; fc < 4; ++fc)
#pragma unroll
            for (int j = 0; j < 4; ++j) {
                float p = __expf(s[fc][j] - m_r[j]);
                s[fc][j] = p;
                rs[j] += p;
            }
#pragma unroll
        for (int j = 0; j < 4; ++j) {
#pragma unroll
            for (int mo = 1; mo < 16; mo <<= 1)
                rs[j] += __shfl_xor(rs[j], mo, 16);
            l_r[j] = l_r[j] * alpha[j] + rs[j];
#pragma unroll
            for (int fd = 0; fd < 4; ++fd) O[fd][j] *= alpha[j];
        }

        // P -> per-wave LDS (swizzled rows of 128B), bf16
#pragma unroll
        for (int fc = 0; fc < 4; ++fc) {
            int col = fc * 16 + lr;
#pragma unroll
            for (int j = 0; j < 4; ++j) {
                int q = kq * 4 + j;
                Pw[q * 64 + ((((col >> 3) ^ (q & 7)) << 3) | (col & 7))] = f2bf(s[fc][j]);
            }
        }
        asm volatile("s_waitcnt lgkmcnt(0)" ::: "memory");

        // PV: O[q=kq*4+j][d=fd*16+lr] += P[q][kv] * V[kv][d]
        bf16x8 pa[2];
        {
            int sw = lr & 7;
            pa[0] = *(const bf16x8*)&Pw[lr * 64 + ((kq ^ sw) << 3)];
            pa[1] = *(const bf16x8*)&Pw[lr * 64 + (((4 + kq) ^ sw) << 3)];
        }
#pragma unroll
        for (int fd = 0; fd < 4; ++fd) {
            int row = fd * 16 + lr;
            int sw = lr & 7;
            bf16x8 v0 = *(const bf16x8*)&Vb[row * 64 + ((kq ^ sw) << 3)];
            bf16x8 v1 = *(const bf16x8*)&Vb[row * 64 + (((4 + kq) ^ sw) << 3)];
            O[fd] = __builtin_amdgcn_mfma_f32_16x16x32_bf16(pa[0], v0, O[fd], 0, 0, 0);
            O[fd] = __builtin_amdgcn_mfma_f32_16x16x32_bf16(pa[1], v1, O[fd], 0, 0, 0);
        }
    };

    stage(0, 0);
    for (int it = 0; it < 15; ++it) {
        stage((it + 1) << 6, (it + 1) & 1);
        asm volatile("s_waitcnt vmcnt(4)\n\ts_barrier" ::: "memory");
        body(it << 6, it & 1);
        asm volatile("s_barrier" ::: "memory");
    }
    asm volatile("s_waitcnt vmcnt(0)\n\ts_barrier" ::: "memory");
    body(15 << 6, 1);

    // finalize + write ctx bf16 [B,S,D]
    short* cb = ctx + ((size_t)(b * SS + q0 + w * 16)) * DD + h * HDD;
#pragma unroll
    for (int j = 0; j < 4; ++j) {
        float inv = 1.0f / l_r[j];
        int qrow = kq * 4 + j;
#pragma unroll
        for (int fd = 0; fd < 4; ++fd)
            cb[(size_t)qrow * DD + fd * 16 + lr] = f2bf(O[fd][j] * inv);
    }
}

// ---------------------------------------------------------------------------
extern "C" void kernel_launch(void* const* d_in, const int* in_sizes, int n_in,
                              void* d_out, int out_size, void* d_ws, size_t ws_size,
                              hipStream_t stream) {
    const float* h    = (const float*)d_in[0];
    const float* mask = (const float*)d_in[1];
    const float* wq   = (const float*)d_in[2];
    const float* bq   = (const float*)d_in[3];
    const float* wk   = (const float*)d_in[4];
    const float* bk   = (const float*)d_in[5];
    const float* wv   = (const float*)d_in[6];
    const float* bv   = (const float*)d_in[7];
    const float* wo   = (const float*)d_in[8];
    const float* bo   = (const float*)d_in[9];
    float* out = (float*)d_out;

    char* base = (char*)d_ws;
    short* x_bf  = (short*)base;                       // 4 MB
    short* w_bf  = (short*)(base + (4u << 20));        // 8 MB
    short* q_bf  = (short*)(base + (12u << 20));       // 4 MB
    short* k_bf  = (short*)(base + (16u << 20));       // 4 MB
    short* v_t   = (short*)(base + (20u << 20));       // 4 MB
    short* ctxbf = (short*)(base + (24u << 20));       // 4 MB

    k_prep_x<<<BSD / 8 / 256, 256, 0, stream>>>(h, x_bf);
    k_prep_w<<<dim3(DD * DD / 8 / 256, 1, 4), 256, 0, stream>>>(wq, wk, wv, wo, w_bf);

    dim3 gqkv(DD / TN, BB * SS / TM, 3);
    k_gemm_qkv<<<gqkv, 256, 0, stream>>>(x_bf, w_bf, bq, bk, bv, q_bf, k_bf, v_t);

    dim3 gattn(SS / 64, BB * HH);
    k_attn<<<gattn, 256, 0, stream>>>(q_bf, k_bf, v_t, mask, ctxbf);

    dim3 gout(DD / TN, BB * SS / TM);
    k_gemm_out<<<gout, 256, 0, stream>>>(ctxbf, w_bf + (size_t)3 * DD * DD, bo, out);
}